// Round 1
// baseline (157.215 us; speedup 1.0000x reference)
//
#include <hip/hip_runtime.h>

#define DM 2048
#define NG 64
#define TPB 64          // tokens per block
#define KC 64           // K chunk
#define NCHUNK (DM / KC)
#define EPSV 1e-8f

typedef __attribute__((ext_vector_type(4))) float f32x4;

__device__ __forceinline__ void stage16(const float* gsrc, float* ldst) {
  __builtin_amdgcn_global_load_lds(
      (const __attribute__((address_space(1))) unsigned int*)gsrc,
      (__attribute__((address_space(3))) unsigned int*)ldst, 16, 0, 0);
}

__global__ __launch_bounds__(256) void TokenMoERouter_kernel(
    const float* __restrict__ x, const float* __restrict__ W,
    float* __restrict__ out, int mtok)
{
  __shared__ float xs[2][TPB * KC];   // 2 x 16 KB, linear [row][col], col pre-swizzled
  __shared__ float ws[2][NG * KC];    // 2 x 16 KB
  __shared__ float lbuf[TPB][NG];     // logits
  __shared__ float ebuf[TPB][NG];     // exp(logit - max)
  __shared__ float invs[TPB];         // 1/sum_e
  __shared__ float rsc[TPB];          // 1/(sum_sel_e + eps*sum_e)
  __shared__ unsigned long long selm[TPB];

  const int tid = threadIdx.x;
  const int tok0 = blockIdx.x * TPB;

  // ---- staging lambda: chunk c -> buffer b (global source pre-swizzled) ----
  auto stage_chunk = [&](int c, int b) {
    const int kbase = c * KC;
#pragma unroll
    for (int i = 0; i < 4; ++i) {
      int idx = i * 256 + tid;        // 0..1023 quad slot
      int r = idx >> 4;               // row 0..63
      int q = idx & 15;               // dest quad within row
      int sq = q ^ (r & 15);          // swizzled source quad
      stage16(x + (size_t)(tok0 + r) * DM + kbase + (sq << 2),
              &xs[b][0] + (idx << 2));
      stage16(W + (size_t)r * DM + kbase + (sq << 2),
              &ws[b][0] + (idx << 2));
    }
  };

  float acc[4][4] = {{0.f}};
  const int t0 = (tid >> 4) << 2;     // 4 tokens owned by this thread
  const int g0 = (tid & 15) << 2;     // 4 groups owned by this thread

  stage_chunk(0, 0);
  __syncthreads();                    // drains vmcnt before first compute

  for (int c = 0; c < NCHUNK; ++c) {
    const int b = c & 1;
    if (c + 1 < NCHUNK) stage_chunk(c + 1, b ^ 1);   // async prefetch into other buffer

#pragma unroll
    for (int kq = 0; kq < KC / 4; ++kq) {
      f32x4 xa[4], wb[4];
#pragma unroll
      for (int i = 0; i < 4; ++i) {
        int row = t0 + i;
        xa[i] = *(const f32x4*)&xs[b][row * KC + ((kq ^ (row & 15)) << 2)];
      }
#pragma unroll
      for (int j = 0; j < 4; ++j) {
        int row = g0 + j;
        wb[j] = *(const f32x4*)&ws[b][row * KC + ((kq ^ (row & 15)) << 2)];
      }
#pragma unroll
      for (int i = 0; i < 4; ++i)
#pragma unroll
        for (int j = 0; j < 4; ++j) {
          acc[i][j] += xa[i].x * wb[j].x;
          acc[i][j] += xa[i].y * wb[j].y;
          acc[i][j] += xa[i].z * wb[j].z;
          acc[i][j] += xa[i].w * wb[j].w;
        }
    }
    __syncthreads();                  // waits prefetch done + compute reads done
  }

  // ---- write logits tile to LDS ----
#pragma unroll
  for (int i = 0; i < 4; ++i) {
    f32x4 v = {acc[i][0], acc[i][1], acc[i][2], acc[i][3]};
    *(f32x4*)&lbuf[t0 + i][g0] = v;
  }
  __syncthreads();

  // ---- per-token softmax + top-8 (one thread per token, spread over 4 waves) ----
  if ((tid & 3) == 0) {
    const int t = tid >> 2;
    const int off = (t << 2) & 63;    // staggered scan order (bank spread)

    float m = -1e30f;
#pragma unroll
    for (int g = 0; g < NG; ++g) {
      int gg = (g + off) & 63;
      m = fmaxf(m, lbuf[t][gg]);
    }
    float sum = 0.f;
#pragma unroll
    for (int g = 0; g < NG; ++g) {
      int gg = (g + off) & 63;
      float e = __expf(lbuf[t][gg] - m);
      ebuf[t][gg] = e;
      sum += e;
    }

    // top-8 over e (same ordering as scores); jax tie-break: lowest index wins
    unsigned long long sel = 0ull;
    float esel = 0.f;
    for (int p = 0; p < 8; ++p) {
      float best = -1.f;
      int bi = 64;
      for (int q = 0; q < 16; ++q) {
        int qq = (q + t) & 15;        // staggered quad order
        f32x4 v = *(const f32x4*)&ebuf[t][qq << 2];
#pragma unroll
        for (int j = 0; j < 4; ++j) {
          int g = (qq << 2) + j;
          bool taken = (sel >> g) & 1ull;
          float val = v[j];
          bool better = !taken && (val > best || (val == best && g < bi));
          best = better ? val : best;
          bi = better ? g : bi;
        }
      }
      sel |= (1ull << bi);
      esel += best;
    }
    invs[t] = 1.f / sum;
    rsc[t] = 1.f / (esel + EPSV * sum);   // routing = e * rsc for selected
    selm[t] = sel;
  }
  __syncthreads();

  // ---- coalesced writer: routing | mask | scores ----
  float* outR = out;
  float* outM = out + (size_t)mtok * NG;
  float* outS = out + 2 * (size_t)mtok * NG;
#pragma unroll
  for (int i = 0; i < 4; ++i) {
    int idx = i * 256 + tid;          // quad index over 64x64 tile
    int t = idx >> 4;
    int q = idx & 15;
    f32x4 e = *(const f32x4*)&ebuf[t][q << 2];
    unsigned long long sel = selm[t];
    float inv = invs[t];
    float rs = rsc[t];
    f32x4 sc, msk, rw;
#pragma unroll
    for (int j = 0; j < 4; ++j) {
      int g = (q << 2) + j;
      float bit = ((sel >> g) & 1ull) ? 1.f : 0.f;
      sc[j] = e[j] * inv;
      msk[j] = bit;
      rw[j] = bit * e[j] * rs;
    }
    size_t goff = (size_t)(tok0 + t) * NG + (q << 2);
    *(f32x4*)&outR[goff] = rw;
    *(f32x4*)&outM[goff] = msk;
    *(f32x4*)&outS[goff] = sc;
  }
}

extern "C" void kernel_launch(void* const* d_in, const int* in_sizes, int n_in,
                              void* d_out, int out_size, void* d_ws, size_t ws_size,
                              hipStream_t stream) {
  const float* x = (const float*)d_in[0];
  const float* W = (const float*)d_in[1];
  float* out = (float*)d_out;
  const int mtok = in_sizes[0] / DM;          // 16384
  dim3 grid(mtok / TPB), block(256);
  hipLaunchKernelGGL(TokenMoERouter_kernel, grid, block, 0, stream, x, W, out, mtok);
}

// Round 2
// 87.967 us; speedup vs baseline: 1.7872x; 1.7872x over previous
//
#include <hip/hip_runtime.h>

#define DM 2048
#define NG 64
#define TPB 64
#define KC 32
#define EPSV 1e-8f

typedef __attribute__((ext_vector_type(4))) float f32x4;

__device__ __forceinline__ void stage16(const float* gsrc, float* ldst) {
  __builtin_amdgcn_global_load_lds(
      (const __attribute__((address_space(1))) unsigned int*)gsrc,
      (__attribute__((address_space(3))) unsigned int*)ldst, 16, 0, 0);
}

// ---------------- Kernel 1: split-K logits GEMM ----------------
// block: 256 threads, 64 tokens x 64 groups tile, K-slice of kper.
// Partial logits for slice sl -> (sl<3 ? out+sl*MN : ws).
__global__ __launch_bounds__(256, 4) void moe_gemm_slice(
    const float* __restrict__ x, const float* __restrict__ W,
    float* __restrict__ out, float* __restrict__ pw,
    int mtok, int nslice, int kper, int shift)
{
  __shared__ float xs[2][TPB * KC];   // 2 x 8 KB
  __shared__ float ws[2][NG * KC];    // 2 x 8 KB

  const int tid = threadIdx.x;
  const int sl  = blockIdx.x & (nslice - 1);
  const int tb  = blockIdx.x >> shift;
  const int tok0 = tb * TPB;
  const int k0   = sl * kper;

  const int u  = tid >> 4;            // token-quad id (0..15)
  const int v  = tid & 15;            // group-quad id (0..15)
  const int t0 = u << 2;
  const int g0 = v << 2;
  const int sx = (u & 7) << 4;        // xa column swizzle (bytes)
  const int sw = (v & 7) << 4;        // wb column swizzle (bytes)

  // stage chunk c into buffer b; LDS dest linear, global source pre-swizzled
  auto stage_chunk = [&](int c, int b) {
    const int kb = k0 + c * KC;
#pragma unroll
    for (int i = 0; i < 2; ++i) {
      int idx = i * 256 + tid;        // 16B slot index, wave-contiguous
      int r = idx >> 3;               // row 0..63
      int q = idx & 7;                // dest quad in row
      int sq = q ^ ((r >> 2) & 7);    // swizzled source quad
      stage16(x + (size_t)(tok0 + r) * DM + kb + (sq << 2), &xs[b][0] + (idx << 2));
    }
#pragma unroll
    for (int i = 0; i < 2; ++i) {
      int idx = i * 256 + tid;
      int r = idx >> 3;
      int q = idx & 7;
      int sq = q ^ ((r >> 2) & 7);
      stage16(W + (size_t)r * DM + kb + (sq << 2), &ws[b][0] + (idx << 2));
    }
  };

  float acc[4][4] = {{0.f}};

  stage_chunk(0, 0);
  __syncthreads();

  const int nchunk = kper / KC;
  for (int c = 0; c < nchunk; ++c) {
    const int b = c & 1;
    if (c + 1 < nchunk) stage_chunk(c + 1, b ^ 1);

#pragma unroll
    for (int kq = 0; kq < KC / 4; ++kq) {
      const char* px = (const char*)&xs[b][t0 * KC] + ((kq << 4) ^ sx);
      const char* pg = (const char*)&ws[b][g0 * KC] + ((kq << 4) ^ sw);
      f32x4 xa[4], wb[4];
#pragma unroll
      for (int i = 0; i < 4; ++i) xa[i] = *(const f32x4*)(px + i * (KC * 4));
#pragma unroll
      for (int j = 0; j < 4; ++j) wb[j] = *(const f32x4*)(pg + j * (KC * 4));
#pragma unroll
      for (int i = 0; i < 4; ++i)
#pragma unroll
        for (int j = 0; j < 4; ++j) {
          acc[i][j] += xa[i].x * wb[j].x;
          acc[i][j] += xa[i].y * wb[j].y;
          acc[i][j] += xa[i].z * wb[j].z;
          acc[i][j] += xa[i].w * wb[j].w;
        }
    }
    __syncthreads();
  }

  float* ps = (sl < 3) ? (out + (size_t)sl * mtok * NG) : pw;
#pragma unroll
  for (int i = 0; i < 4; ++i) {
    f32x4 r = {acc[i][0], acc[i][1], acc[i][2], acc[i][3]};
    *(f32x4*)&ps[(size_t)(tok0 + t0 + i) * NG + g0] = r;
  }
}

// ---------------- Kernel 2: reduce + softmax + top-8 + write ----------------
// 256 threads = 32 tokens/block, 8 lanes per token (each lane owns 8 groups).
__global__ __launch_bounds__(256) void moe_finish(
    float* __restrict__ out, const float* __restrict__ pw, int mtok, int nslice)
{
  const int tid = threadIdx.x;
  const int t   = blockIdx.x * 32 + (tid >> 3);
  const int l8  = tid & 7;
  const size_t MN = (size_t)mtok * NG;
  const size_t base = (size_t)t * NG + (l8 << 3);

  f32x4 a0 = {0.f, 0.f, 0.f, 0.f}, a1 = {0.f, 0.f, 0.f, 0.f};
  for (int s = 0; s < nslice; ++s) {
    const float* p = (s < 3) ? (out + (size_t)s * MN) : pw;
    a0 += *(const f32x4*)&p[base];
    a1 += *(const f32x4*)&p[base + 4];
  }

  float l[8];
#pragma unroll
  for (int j = 0; j < 4; ++j) { l[j] = a0[j]; l[j + 4] = a1[j]; }

  // group max over 64 (8 local + 3-step shuffle within 8-lane group)
  float m = l[0];
#pragma unroll
  for (int j = 1; j < 8; ++j) m = fmaxf(m, l[j]);
#pragma unroll
  for (int msk = 1; msk < 8; msk <<= 1) m = fmaxf(m, __shfl_xor(m, msk));

  float e[8];
  float sum = 0.f;
#pragma unroll
  for (int j = 0; j < 8; ++j) { e[j] = __expf(l[j] - m); sum += e[j]; }
#pragma unroll
  for (int msk = 1; msk < 8; msk <<= 1) sum += __shfl_xor(sum, msk);

  // top-8: repeated (val, lowest-idx) argmax via shuffle reduce
  unsigned taken = 0;
  float esel = 0.f;
  for (int p = 0; p < 8; ++p) {
    float bv = -1.f;
    int bi = 127;
#pragma unroll
    for (int j = 0; j < 8; ++j) {
      bool avail = !((taken >> j) & 1u);
      float vv = e[j];
      int g = (l8 << 3) + j;
      bool better = avail && (vv > bv || (vv == bv && g < bi));
      bv = better ? vv : bv;
      bi = better ? g : bi;
    }
#pragma unroll
    for (int msk = 1; msk < 8; msk <<= 1) {
      float ov = __shfl_xor(bv, msk);
      int oi = __shfl_xor(bi, msk);
      bool better = (ov > bv) || (ov == bv && oi < bi);
      bv = better ? ov : bv;
      bi = better ? oi : bi;
    }
    esel += bv;
    if ((bi >> 3) == l8) taken |= 1u << (bi & 7);
  }

  const float inv = 1.f / sum;
  const float rsc = 1.f / (esel + EPSV * sum);

  f32x4 r0, r1, m0, m1, s0, s1;
#pragma unroll
  for (int j = 0; j < 4; ++j) {
    float bitL = ((taken >> j) & 1u) ? 1.f : 0.f;
    float bitH = ((taken >> (j + 4)) & 1u) ? 1.f : 0.f;
    s0[j] = e[j] * inv;      s1[j] = e[j + 4] * inv;
    m0[j] = bitL;            m1[j] = bitH;
    r0[j] = bitL * e[j] * rsc;
    r1[j] = bitH * e[j + 4] * rsc;
  }
  *(f32x4*)&out[base]            = r0;
  *(f32x4*)&out[base + 4]        = r1;
  *(f32x4*)&out[MN + base]       = m0;
  *(f32x4*)&out[MN + base + 4]   = m1;
  *(f32x4*)&out[2 * MN + base]     = s0;
  *(f32x4*)&out[2 * MN + base + 4] = s1;
}

extern "C" void kernel_launch(void* const* d_in, const int* in_sizes, int n_in,
                              void* d_out, int out_size, void* d_ws, size_t ws_size,
                              hipStream_t stream) {
  const float* x = (const float*)d_in[0];
  const float* W = (const float*)d_in[1];
  float* out = (float*)d_out;
  const int mtok = in_sizes[0] / DM;          // 16384
  const size_t MN = (size_t)mtok * NG;

  int nslice, shift;
  if (ws_size >= MN * sizeof(float)) { nslice = 4; shift = 2; }
  else                               { nslice = 2; shift = 1; }
  const int kper = DM / nslice;

  dim3 blk(256);
  dim3 g1((mtok / TPB) << shift);
  hipLaunchKernelGGL(moe_gemm_slice, g1, blk, 0, stream,
                     x, W, out, (float*)d_ws, mtok, nslice, kper, shift);
  dim3 g2(mtok / 32);
  hipLaunchKernelGGL(moe_finish, g2, blk, 0, stream, out, (const float*)d_ws, mtok, nslice);
}